// Round 5
// baseline (240.279 us; speedup 1.0000x reference)
//
#include <hip/hip_runtime.h>

// ---------------------------------------------------------------------------
// Debiased Representation Loss — fused MI355X implementation (R5).
// R5: SYMMETRY — sim (zn.zn^T) and base_sim (bn.bn^T) are symmetric, so the
// contrastive kernel runs only upper-triangle tiles (528 blocks vs 1024).
// Off-diag tiles serve rows ib directly and rows jc via an LDS transpose of
// the bf16 sim values (svT) + mask bits (maskT); attn (f1z.f2z^T, NOT
// symmetric) runs both directions (2 x K=256). Total K-work: 1.835M -> 1.073M.
// Also: 4 graph nodes (normalize+convert+softmax+zero fused; no memset).
// ---------------------------------------------------------------------------

#define B_N   4096
#define D_N   768
#define HID_N 256
#define NCLS  200

typedef __attribute__((ext_vector_type(8))) short v8s;   // 8 x bf16 (4 VGPRs)
typedef __attribute__((ext_vector_type(4))) float v4f;   // MFMA accumulator

__device__ __forceinline__ unsigned short f2bf(float x) {
    unsigned int u = __float_as_uint(x);
    unsigned int r = (u + 0x7FFFu + ((u >> 16) & 1u)) >> 16;
    return (unsigned short)r;
}
__device__ __forceinline__ float bf2f(unsigned short h) {
    return __uint_as_float((unsigned int)h << 16);
}

// async global->LDS, 16 B per lane; lane i lands at ldsbase + i*16
__device__ __forceinline__ void gld16(const unsigned short* g, unsigned short* l) {
    __builtin_amdgcn_global_load_lds(
        (__attribute__((address_space(1))) void*)g,
        (__attribute__((address_space(3))) void*)l, 16, 0, 0);
}

#define ZERO_ACC(a) { _Pragma("unroll") for (int _i = 0; _i < 4; _i++) \
    _Pragma("unroll") for (int _j = 0; _j < 4; _j++) a[_i][_j] = (v4f){0.f,0.f,0.f,0.f}; }

// ---------------------------------------------------------------------------
// Shared mini-GEMM: block tile 128x128, NT bf16; 2x2 wave grid, 4x4 MFMA
// tiles per wave. global_load_lds width-16 staging, XOR-swizzled unpadded
// LDS rows (stride 64 ushorts). 0 bank conflicts measured R2-R4.
// ---------------------------------------------------------------------------
__device__ __forceinline__ void mm_tile128(
    const unsigned short* __restrict__ Ag, const unsigned short* __restrict__ Bg,
    int aRow0, int bRow0, int K,
    unsigned short* Al, unsigned short* Bl, v4f acc[4][4])
{
    const int tid = threadIdx.x;
    const int lane = tid & 63, wave = tid >> 6, quad = lane >> 4, col = lane & 15;
    const int wr = wave >> 1, wc = wave & 1;
    const int r8 = lane >> 3;
    const int kbl = (lane & 7) ^ r8;
    const int sw  = col & 7;
    for (int kc = 0; kc < K; kc += 64) {
        __syncthreads();
        #pragma unroll
        for (int s = 0; s < 4; s++) {
            int rowbase = s * 32 + wave * 8;
            gld16(Ag + (size_t)(aRow0 + rowbase + r8) * K + kc + kbl * 8,
                  Al + rowbase * 64);
            gld16(Bg + (size_t)(bRow0 + rowbase + r8) * K + kc + kbl * 8,
                  Bl + rowbase * 64);
        }
        __syncthreads();
        #pragma unroll
        for (int kk = 0; kk < 2; kk++) {
            int ko = (((kk << 2) + quad) ^ sw) << 3;
            v8s af[4], bf[4];
            #pragma unroll
            for (int t = 0; t < 4; t++) {
                af[t] = *(const v8s*)(Al + (wr * 64 + t * 16 + col) * 64 + ko);
                bf[t] = *(const v8s*)(Bl + (wc * 64 + t * 16 + col) * 64 + ko);
            }
            #pragma unroll
            for (int tr = 0; tr < 4; tr++)
                #pragma unroll
                for (int tc = 0; tc < 4; tc++)
                    acc[tr][tc] = __builtin_amdgcn_mfma_f32_16x16x32_bf16(
                        af[tr], bf[tc], acc[tr][tc], 0, 0, 0);
        }
    }
}

// ---------------------------------------------------------------------------
// Kernel 1: fused pre-pass. blocks [0,4096): row normalize; [4096,4104):
// weight bf16 conversion (+ accums zeroing); [4104,4360): softmax partials.
// ---------------------------------------------------------------------------
__global__ __launch_bounds__(256) void pre_all(
    const float* __restrict__ z, const float* __restrict__ base,
    const float* __restrict__ w1, const float* __restrict__ w2,
    const float* __restrict__ logits, const int* __restrict__ oldi,
    const int* __restrict__ newi,
    unsigned short* __restrict__ zn, unsigned short* __restrict__ bn,
    unsigned short* __restrict__ zb,
    unsigned short* __restrict__ o1, unsigned short* __restrict__ o2,
    float* __restrict__ mpart, float* __restrict__ accums)
{
    int tid = threadIdx.x;
    if (blockIdx.x < B_N) {
        int row = blockIdx.x;
        __shared__ float ws1[4], ws2[4];
        const float* zr = z    + (size_t)row * D_N;
        const float* br = base + (size_t)row * D_N;
        float z0 = zr[tid], z1 = zr[tid + 256], z2 = zr[tid + 512];
        float b0 = br[tid], b1 = br[tid + 256], b2 = br[tid + 512];
        float s1 = z0*z0 + z1*z1 + z2*z2;
        float s2 = b0*b0 + b1*b1 + b2*b2;
        #pragma unroll
        for (int m = 32; m > 0; m >>= 1) { s1 += __shfl_xor(s1, m); s2 += __shfl_xor(s2, m); }
        if ((tid & 63) == 0) { ws1[tid >> 6] = s1; ws2[tid >> 6] = s2; }
        __syncthreads();
        float t1 = ws1[0] + ws1[1] + ws1[2] + ws1[3];
        float t2 = ws2[0] + ws2[1] + ws2[2] + ws2[3];
        float sc1 = 1.0f / fmaxf(sqrtf(t1), 1e-12f);
        float sc2 = 1.0f / fmaxf(sqrtf(t2), 1e-12f);
        size_t o = (size_t)row * D_N;
        zn[o+tid] = f2bf(z0*sc1); zn[o+tid+256] = f2bf(z1*sc1); zn[o+tid+512] = f2bf(z2*sc1);
        bn[o+tid] = f2bf(b0*sc2); bn[o+tid+256] = f2bf(b1*sc2); bn[o+tid+512] = f2bf(b2*sc2);
        zb[o+tid] = f2bf(z0);     zb[o+tid+256] = f2bf(z1);     zb[o+tid+512] = f2bf(z2);
        return;
    }
    if (blockIdx.x < B_N + 8) {                  // weight conversion
        int b2 = blockIdx.x - B_N;               // 0..7
        if (b2 == 0 && tid < 4) accums[tid] = 0.0f;
        const float* src = (b2 < 4) ? w1 : w2;
        unsigned short* dst = (b2 < 4) ? o1 : o2;
        int base2 = (b2 & 3) * 49152 + tid;
        #pragma unroll 4
        for (int i = 0; i < 192; i++) dst[base2 + i * 256] = f2bf(src[base2 + i * 256]);
        return;
    }
    // softmax partials: 256 blocks x 16 rows
    {
        __shared__ int act[256];
        __shared__ float accs[4][256];
        int sb = blockIdx.x - (B_N + 8);
        int lane = tid & 63, wave = tid >> 6;
        if (tid < NCLS) act[tid] = (tid < 100) ? oldi[tid] : newi[tid - 100];
        accs[0][tid] = 0.f; accs[1][tid] = 0.f; accs[2][tid] = 0.f; accs[3][tid] = 0.f;
        __syncthreads();
        int a0 = act[lane], a1 = act[lane + 64], a2 = act[lane + 128];
        int a3 = (lane < 8) ? act[lane + 192] : 0;
        int r0 = sb * 16 + wave * 4;
        float c0 = 0.f, c1 = 0.f, c2 = 0.f, c3 = 0.f;
        for (int i = 0; i < 4; i++) {
            const float* lr = logits + (size_t)(r0 + i) * NCLS;
            float x0 = lr[a0], x1 = lr[a1], x2 = lr[a2];
            float x3 = (lane < 8) ? lr[a3] : -3.0e38f;
            float m = fmaxf(fmaxf(x0, x1), fmaxf(x2, x3));
            #pragma unroll
            for (int s = 32; s > 0; s >>= 1) m = fmaxf(m, __shfl_xor(m, s));
            float e0 = __expf(x0 - m), e1 = __expf(x1 - m), e2 = __expf(x2 - m);
            float e3 = (lane < 8) ? __expf(x3 - m) : 0.f;
            float sm = e0 + e1 + e2 + e3;
            #pragma unroll
            for (int s = 32; s > 0; s >>= 1) sm += __shfl_xor(sm, s);
            float inv = 1.0f / sm;
            c0 += e0 * inv; c1 += e1 * inv; c2 += e2 * inv; c3 += e3 * inv;
        }
        accs[wave][lane] = c0; accs[wave][lane + 64] = c1; accs[wave][lane + 128] = c2;
        if (lane < 8) accs[wave][lane + 192] = c3;
        __syncthreads();
        mpart[(size_t)tid * 256 + sb] =
            accs[0][tid] + accs[1][tid] + accs[2][tid] + accs[3][tid];
    }
}

// ---------------------------------------------------------------------------
// Kernel 2: fz = z @ W^T + b for BOTH weights in one launch. grid (32, 4).
// ---------------------------------------------------------------------------
__global__ __launch_bounds__(256, 2) void fz_gemm(
    const unsigned short* __restrict__ zb,
    const unsigned short* __restrict__ w1b, const unsigned short* __restrict__ w2b,
    const float* __restrict__ b1, const float* __restrict__ b2,
    unsigned short* __restrict__ f1z, unsigned short* __restrict__ f2z)
{
    __shared__ __align__(16) unsigned short Al[128 * 64];
    __shared__ __align__(16) unsigned short Bl[128 * 64];
    int which = blockIdx.y >> 1;
    const unsigned short* wb = which ? w2b : w1b;
    const float* bias = which ? b2 : b1;
    unsigned short* outz = which ? f2z : f1z;
    int mBase = blockIdx.x * 128, nBase = (blockIdx.y & 1) * 128;
    v4f acc[4][4]; ZERO_ACC(acc);
    mm_tile128(zb, wb, mBase, nBase, D_N, Al, Bl, acc);
    int tid = threadIdx.x, lane = tid & 63, wave = tid >> 6, quad = lane >> 4, col = lane & 15;
    int wr = wave >> 1, wc = wave & 1;
    #pragma unroll
    for (int tr = 0; tr < 4; tr++)
        #pragma unroll
        for (int tc = 0; tc < 4; tc++) {
            int gcol = nBase + wc * 64 + tc * 16 + col;
            float bv = bias[gcol];
            #pragma unroll
            for (int reg = 0; reg < 4; reg++) {
                int grow = mBase + wr * 64 + tr * 16 + quad * 4 + reg;
                outz[(size_t)grow * HID_N + gcol] = f2bf(acc[tr][tc][reg] + bv);
            }
        }
}

// ---------------------------------------------------------------------------
// Kernel 3: symmetric fused contrastive main. grid 528 = upper triangle of
// 32x32 tile pairs. Off-diag tile (ib<jc): mask+sim once, attn both ways;
// transposed side reads sv/mask from LDS (svT stride 130 = ~2-way banks).
// Partials: direct rows ib at chunks {2jc,2jc+1}; transposed rows jc at
// chunks {2ib,2ib+1}; diag covers its own pair -> every slot written once.
// ---------------------------------------------------------------------------
__global__ __launch_bounds__(256, 2) void main_fused(
    const unsigned short* __restrict__ zn, const unsigned short* __restrict__ bn,
    const unsigned short* __restrict__ f1z, const unsigned short* __restrict__ f2z,
    float* __restrict__ partials)
{
    __shared__ __align__(16) unsigned short Sa[128 * 64];
    __shared__ __align__(16) unsigned short Sb[128 * 64];
    __shared__ __align__(16) unsigned short svT[128 * 130];
    __shared__ unsigned short maskT[128 * 8];

    // decode upper-triangle (ib, jc), jc >= ib
    int k = blockIdx.x, ib = 0;
    while (k >= 32 - ib) { k -= 32 - ib; ib++; }
    int jc = ib + k;
    bool diag = (ib == jc);

    int tid = threadIdx.x, lane = tid & 63, wave = tid >> 6, quad = lane >> 4, col = lane & 15;
    int wr = wave >> 1, wc = wave & 1;
    int rBase = ib * 128 + wr * 64;
    int cBase = jc * 128 + wc * 64;

    v4f acc[4][4];

    // --- phase M: mask GEMM (bn.bn^T), K=768 ---
    ZERO_ACC(acc);
    mm_tile128(bn, bn, ib * 128, jc * 128, D_N, Sa, Sb, acc);
    unsigned long long mb = 0ull;
    #pragma unroll
    for (int tr = 0; tr < 4; tr++)
        #pragma unroll
        for (int tc = 0; tc < 4; tc++)
            #pragma unroll
            for (int reg = 0; reg < 4; reg++) {
                int grow = rBase + tr * 16 + quad * 4 + reg;
                int gcol = cBase + tc * 16 + col;
                if (acc[tr][tc][reg] > 0.05f && grow != gcol)
                    mb |= 1ull << (tr * 16 + tc * 4 + reg);
            }
    if (!diag) {
        // maskT[j][wrM*4+quadM] bit (trM*4+regM) <-> i = wrM*64+trM*16+quadM*4+regM
        #pragma unroll
        for (int tc = 0; tc < 4; tc++) {
            unsigned int w = 0;
            #pragma unroll
            for (int tr = 0; tr < 4; tr++)
                #pragma unroll
                for (int reg = 0; reg < 4; reg++)
                    if ((mb >> (tr * 16 + tc * 4 + reg)) & 1ull) w |= 1u << (tr * 4 + reg);
            int j = wc * 64 + tc * 16 + col;
            maskT[j * 8 + wr * 4 + quad] = (unsigned short)w;
        }
    }

    // --- phase S: sim GEMM (zn.zn^T), K=768 ---
    ZERO_ACC(acc);
    mm_tile128(zn, zn, ib * 128, jc * 128, D_N, Sa, Sb, acc);
    float dsumD[16];
    #pragma unroll
    for (int i = 0; i < 16; i++) dsumD[i] = 0.f;
    unsigned int svp[4][4][2];
    #pragma unroll
    for (int tr = 0; tr < 4; tr++)
        #pragma unroll
        for (int tc = 0; tc < 4; tc++) {
            #pragma unroll
            for (int reg = 0; reg < 4; reg++) {
                float sv = acc[tr][tc][reg];
                int grow = rBase + tr * 16 + quad * 4 + reg;
                int gcol = cBase + tc * 16 + col;
                if (grow != gcol) dsumD[tr * 4 + reg] += __expf(sv * 10.0f);
            }
            svp[tr][tc][0] = ((unsigned int)f2bf(acc[tr][tc][1]) << 16) | f2bf(acc[tr][tc][0]);
            svp[tr][tc][1] = ((unsigned int)f2bf(acc[tr][tc][3]) << 16) | f2bf(acc[tr][tc][2]);
        }
    if (!diag) {
        // svT[j*130 + i] = bf16 sim(i,j); i0 multiple of 4 -> 4B-aligned b32 writes
        #pragma unroll
        for (int tr = 0; tr < 4; tr++)
            #pragma unroll
            for (int tc = 0; tc < 4; tc++) {
                int j = wc * 64 + tc * 16 + col;
                int i0 = wr * 64 + tr * 16 + quad * 4;
                *(unsigned int*)(&svT[j * 130 + i0])     = svp[tr][tc][0];
                *(unsigned int*)(&svT[j * 130 + i0 + 2]) = svp[tr][tc][1];
            }
    }

    // --- phase A1: attn direct (f1z[ib].f2z[jc]^T), K=256 ---
    ZERO_ACC(acc);
    mm_tile128(f1z, f2z, ib * 128, jc * 128, HID_N, Sa, Sb, acc);
    {
        float lsum[16], asum[16], nnf[16];
        #pragma unroll
        for (int i = 0; i < 16; i++) { lsum[i] = 0.f; asum[i] = 0.f; nnf[i] = 0.f; }
        #pragma unroll
        for (int tr = 0; tr < 4; tr++)
            #pragma unroll
            for (int tc = 0; tc < 4; tc++)
                #pragma unroll
                for (int reg = 0; reg < 4; reg++) {
                    if ((mb >> (tr * 16 + tc * 4 + reg)) & 1ull) {
                        int slot = tr * 4 + reg;
                        float e = __expf(acc[tr][tc][reg]);
                        unsigned int pk = svp[tr][tc][reg >> 1];
                        float sv = bf2f((unsigned short)((reg & 1) ? (pk >> 16) : (pk & 0xFFFF)));
                        lsum[slot] += e;
                        asum[slot] += e * sv;
                        nnf[slot] += 1.f;
                    }
                }
        #pragma unroll
        for (int i = 0; i < 16; i++) {
            #pragma unroll
            for (int m = 1; m < 16; m <<= 1) {
                lsum[i] += __shfl_xor(lsum[i], m);
                asum[i] += __shfl_xor(asum[i], m);
                dsumD[i] += __shfl_xor(dsumD[i], m);
                nnf[i]  += __shfl_xor(nnf[i], m);
            }
            if (col == 0) {
                int row = rBase + (i >> 2) * 16 + quad * 4 + (i & 3);
                float4 v; v.x = lsum[i]; v.y = asum[i]; v.z = dsumD[i]; v.w = nnf[i];
                *(float4*)(partials + ((size_t)row * 64 + jc * 2 + wc) * 4) = v;
            }
        }
    }

    if (diag) return;

    // --- phase A2: attn transposed (f1z[jc].f2z[ib]^T), K=256 ---
    ZERO_ACC(acc);
    mm_tile128(f1z, f2z, jc * 128, ib * 128, HID_N, Sa, Sb, acc);
    {
        float lsum[16], asum[16], dsum[16], nnf[16];
        #pragma unroll
        for (int i = 0; i < 16; i++) { lsum[i] = 0.f; asum[i] = 0.f; dsum[i] = 0.f; nnf[i] = 0.f; }
        #pragma unroll
        for (int tr = 0; tr < 4; tr++)
            #pragma unroll
            for (int reg = 0; reg < 4; reg++) {
                int slot = tr * 4 + reg;
                int rp = wr * 64 + tr * 16 + quad * 4 + reg;          // local j
                unsigned int mwv = maskT[rp * 8 + wc * 4 + (col >> 2)];
                unsigned int mybit = 1u << ((col & 3));
                #pragma unroll
                for (int tc = 0; tc < 4; tc++) {
                    float sv = bf2f(svT[rp * 130 + wc * 64 + tc * 16 + col]);
                    dsum[slot] += __expf(sv * 10.0f);
                    if (mwv & (mybit << (tc * 4))) {
                        float e = __expf(acc[tr][tc][reg]);
                        lsum[slot] += e;
                        asum[slot] += e * sv;
                        nnf[slot] += 1.f;
                    }
                }
            }
        #pragma unroll
        for (int i = 0; i < 16; i++) {
            #pragma unroll
            for (int m = 1; m < 16; m <<= 1) {
                lsum[i] += __shfl_xor(lsum[i], m);
                asum[i] += __shfl_xor(asum[i], m);
                dsum[i] += __shfl_xor(dsum[i], m);
                nnf[i]  += __shfl_xor(nnf[i], m);
            }
            if (col == 0) {
                int row = jc * 128 + wr * 64 + (i >> 2) * 16 + quad * 4 + (i & 3);
                float4 v; v.x = lsum[i]; v.y = asum[i]; v.z = dsum[i]; v.w = nnf[i];
                *(float4*)(partials + ((size_t)row * 64 + ib * 2 + wc) * 4) = v;
            }
        }
    }
}

// ---------------------------------------------------------------------------
// Kernel 4: reduce per-row partials (64 blocks, 4 lanes/row); last block
// computes entropy term from mpart + final combine -> d_out[0].
// ---------------------------------------------------------------------------
__global__ __launch_bounds__(256) void row_reduce_fin(
    const float* __restrict__ partials, const float* __restrict__ mpart,
    float* __restrict__ acc, float* __restrict__ out)
{
    int tid = threadIdx.x;
    int row = blockIdx.x * 64 + (tid >> 2);
    int sub = tid & 3;
    const float4* p = (const float4*)partials + (size_t)row * 64 + sub * 16;
    float L = 0.f, A = 0.f, Dn = 0.f, NN = 0.f;
    #pragma unroll
    for (int c = 0; c < 16; c++) { float4 v = p[c]; L += v.x; A += v.y; Dn += v.z; NN += v.w; }
    #pragma unroll
    for (int m = 1; m < 4; m <<= 1) {
        L += __shfl_xor(L, m); A += __shfl_xor(A, m);
        Dn += __shfl_xor(Dn, m); NN += __shfl_xor(NN, m);
    }
    float per = 0.f, val = 0.f;
    if (sub == 0 && NN > 0.5f) {
        per = (logf(Dn + 1e-8f) - 10.0f * (A / L)) / NN;
        val = 1.0f;
    }
    __shared__ float red[256];
    __shared__ float r2s[256];
    __shared__ int amLast;
    red[tid] = per; r2s[tid] = val; __syncthreads();
    for (int s = 128; s > 0; s >>= 1) {
        if (tid < s) { red[tid] += red[tid + s]; r2s[tid] += r2s[tid + s]; }
        __syncthreads();
    }
    if (tid == 0) {
        atomicAdd(&acc[0], red[0]);
        atomicAdd(&acc[1], r2s[0]);
        __threadfence();
        int old = atomicAdd((int*)&acc[2], 1);
        amLast = (old == (int)gridDim.x - 1);
    }
    __syncthreads();
    if (!amLast) return;

    __shared__ float bcast[2];
    float pcl = 0.0f;
    if (tid < NCLS) {
        const float4* mp = (const float4*)(mpart + (size_t)tid * 256);
        float s = 0.f;
        #pragma unroll
        for (int c = 0; c < 64; c++) { float4 v = mp[c]; s += v.x + v.y + v.z + v.w; }
        pcl = s * (1.0f / 4096.0f);
    }
    red[tid] = (tid < 100) ? pcl : 0.0f; __syncthreads();
    for (int s = 128; s > 0; s >>= 1) { if (tid < s) red[tid] += red[tid + s]; __syncthreads(); }
    if (tid == 0) bcast[0] = red[0];
    __syncthreads();
    red[tid] = (tid >= 100 && tid < NCLS) ? pcl : 0.0f; __syncthreads();
    for (int s = 128; s > 0; s >>= 1) { if (tid < s) red[tid] += red[tid + s]; __syncthreads(); }
    if (tid == 0) bcast[1] = red[0];
    __syncthreads();
    float p_old = bcast[0], p_new = bcast[1];

    float t = 0.0f;
    if (tid < 100)       { float q = pcl / (p_old + 1e-8f); t = q * logf(q + 1e-8f); }
    else if (tid < NCLS) { float q = pcl / (p_new + 1e-8f); t = q * logf(q + 1e-8f); }
    red[tid] = t; __syncthreads();
    for (int s = 128; s > 0; s >>= 1) { if (tid < s) red[tid] += red[tid + s]; __syncthreads(); }

    if (tid == 0) {
        float s0 = __hip_atomic_load(&acc[0], __ATOMIC_RELAXED, __HIP_MEMORY_SCOPE_AGENT);
        float s1 = __hip_atomic_load(&acc[1], __ATOMIC_RELAXED, __HIP_MEMORY_SCOPE_AGENT);
        float loss_inter = p_old * logf(p_old + 1e-8f) + p_new * logf(p_new + 1e-8f)
                           + 0.69314718056f;
        float loss_entropy = loss_inter + red[0] + 2.0f * 4.60517018599f;
        float lc = (s1 > 0.5f) ? s0 / s1 : 0.0f;
        out[0] = loss_entropy + lc;
    }
}

// ---------------------------------------------------------------------------
extern "C" void kernel_launch(void* const* d_in, const int* in_sizes, int n_in,
                              void* d_out, int out_size, void* d_ws, size_t ws_size,
                              hipStream_t stream)
{
    const float* z_u    = (const float*)d_in[0];
    const float* logits = (const float*)d_in[1];
    const int*   oldi   = (const int*)d_in[2];
    const int*   newi   = (const int*)d_in[3];
    const float* basef  = (const float*)d_in[4];
    const float* f1w    = (const float*)d_in[5];
    const float* f1b    = (const float*)d_in[6];
    const float* f2w    = (const float*)d_in[7];
    const float* f2b    = (const float*)d_in[8];
    float* out = (float*)d_out;

    unsigned short* zn   = (unsigned short*)d_ws;          // [B][D] bf16
    unsigned short* bn   = zn  + (size_t)B_N * D_N;
    unsigned short* zb   = bn  + (size_t)B_N * D_N;
    unsigned short* w1b  = zb  + (size_t)B_N * D_N;        // [HID][D]
    unsigned short* w2b  = w1b + (size_t)HID_N * D_N;
    unsigned short* f1z  = w2b + (size_t)HID_N * D_N;      // [B][HID]
    unsigned short* f2z  = f1z + (size_t)B_N * HID_N;
    float* partials = (float*)(f2z + (size_t)B_N * HID_N); // [B][64][4]
    float* mpart    = partials + (size_t)B_N * 64 * 4;     // [256 class][256 blk]
    float* accums   = mpart + 256 * 256;                   // [2] + counter

    pre_all<<<B_N + 8 + 256, 256, 0, stream>>>(z_u, basef, f1w, f2w, logits, oldi, newi,
                                               zn, bn, zb, w1b, w2b, mpart, accums);
    fz_gemm<<<dim3(B_N / 128, 4), 256, 0, stream>>>(zb, w1b, w2b, f1b, f2b, f1z, f2z);
    main_fused<<<528, 256, 0, stream>>>(zn, bn, f1z, f2z, partials);
    row_reduce_fin<<<64, 256, 0, stream>>>(partials, mpart, accums, out);
}